// Round 1
// baseline (153.577 us; speedup 1.0000x reference)
//
#include <hip/hip_runtime.h>
#include <hip/hip_bf16.h>

// Problem constants
#define NN 64
#define BB 256
#define DD 1792
#define KK 35
#define PP 10
#define DQ 448          // D / 4 (float4s per row)
#define MROWS 16        // n-rows per main block
#define NCHUNK 4        // N / MROWS

// ---------------------------------------------------------------------------
// K1: Gf = gamma * W_net (P x D), sG[p] = sum(Gf[p]), zc[p] = dot(beta,Wnet[p]) + b_net[p]
// ---------------------------------------------------------------------------
__global__ void prep_gf(const float* __restrict__ gamma, const float* __restrict__ beta,
                        const float* __restrict__ Wnet, const float* __restrict__ bnet,
                        float* __restrict__ GF, float* __restrict__ SG, float* __restrict__ ZC) {
    const int p = blockIdx.x;
    const int tid = threadIdx.x;
    float sg = 0.f, sb = 0.f;
#pragma unroll
    for (int j = 0; j < 7; ++j) {
        int d = j * 256 + tid;
        float wv = Wnet[p * DD + d];
        float g = gamma[d] * wv;
        GF[p * DD + d] = g;
        sg += g;
        sb += beta[d] * wv;
    }
#pragma unroll
    for (int off = 32; off > 0; off >>= 1) {
        sg += __shfl_xor(sg, off);
        sb += __shfl_xor(sb, off);
    }
    __shared__ float rs[4][2];
    if ((tid & 63) == 0) { rs[tid >> 6][0] = sg; rs[tid >> 6][1] = sb; }
    __syncthreads();
    if (tid == 0) {
        float a = 0.f, c = 0.f;
#pragma unroll
        for (int w = 0; w < 4; ++w) { a += rs[w][0]; c += rs[w][1]; }
        SG[p] = a;
        ZC[p] = c + bnet[p];
    }
}

// ---------------------------------------------------------------------------
// K2: bank[b][r] = dot(task[b], Wtok[r]) + btok[r]   (r in [0, P*D))
//     ptok[b][d] = dot(task[b], Wptok[d]) + bptok[d]
// Block: 256 threads own 256 consecutive rows; W row cached in registers,
// loop over 32 b's with task_id staged in LDS (broadcast reads).
// grid = (77, 8): blocks 0..69 -> bank rows, 70..76 -> ptok rows.
// ---------------------------------------------------------------------------
__global__ void prep_bank(const float* __restrict__ task,
                          const float* __restrict__ Wtok, const float* __restrict__ btok,
                          const float* __restrict__ Wptok, const float* __restrict__ bptok,
                          float* __restrict__ bank, float* __restrict__ ptok) {
    __shared__ float ti[32 * KK];
    const int tid = threadIdx.x;
    const int b0 = blockIdx.y * 32;
    for (int i = tid; i < 32 * KK; i += 256) ti[i] = task[b0 * KK + i];

    const int r = blockIdx.x * 256 + tid;
    const bool isbank = (r < PP * DD);
    const int rr = isbank ? r : (r - PP * DD);
    const float* __restrict__ W = isbank ? Wtok : Wptok;
    const float bias = isbank ? btok[r] : bptok[rr];

    float w[KK];
#pragma unroll
    for (int k = 0; k < KK; ++k) w[k] = W[rr * KK + k];

    __syncthreads();
#pragma unroll 1
    for (int bb = 0; bb < 32; ++bb) {
        float acc = bias;
#pragma unroll
        for (int k = 0; k < KK; ++k) acc = fmaf(ti[bb * KK + k], w[k], acc);
        const int b = b0 + bb;
        if (isbank) bank[b * (PP * DD) + r] = acc;
        else        ptok[b * DD + rr]       = acc;
    }
}

// ---------------------------------------------------------------------------
// K3 (main): per block: b fixed, 16 n-rows. 448 threads, 1 float4/thread/row.
// Phase 1: t = X + ptok; accumulate {sum, sumsq, 10 Gf-dots}; reduce; w=sigmoid.
// Phase 2: out = X + sum_p w[p] * bank[b][p][:], bank cached in 10 float4 regs.
// ---------------------------------------------------------------------------
__global__ __launch_bounds__(448) void main_kernel(
    const float* __restrict__ X, const float* __restrict__ BANK,
    const float* __restrict__ PTOK, const float* __restrict__ GF,
    const float* __restrict__ SG, const float* __restrict__ ZC,
    float* __restrict__ OUT) {
    const int tid = threadIdx.x;
    const int b = blockIdx.y;
    const int n0 = blockIdx.x * MROWS;

    const float4* __restrict__ X4 = (const float4*)X;
    const float4* __restrict__ B4 = (const float4*)BANK;
    const float4* __restrict__ G4 = (const float4*)GF;
    const float4* __restrict__ P4 = (const float4*)PTOK;
    float4* __restrict__ O4 = (float4*)OUT;

    __shared__ float red[7][12];
    __shared__ float wlds[MROWS][PP];

    float4 gf[PP];
#pragma unroll
    for (int p = 0; p < PP; ++p) gf[p] = G4[p * DQ + tid];
    const float4 ptk = P4[b * DQ + tid];

    // ---- phase 1: weights ----
    float4 xn = X4[((n0 + 0) * BB + b) * DQ + tid];
#pragma unroll 1
    for (int r = 0; r < MROWS; ++r) {
        float4 x = xn;
        if (r < MROWS - 1) xn = X4[((n0 + r + 1) * BB + b) * DQ + tid];

        float4 t;
        t.x = x.x + ptk.x; t.y = x.y + ptk.y; t.z = x.z + ptk.z; t.w = x.w + ptk.w;

        float s1 = t.x + t.y + t.z + t.w;
        float s2 = t.x * t.x;
        s2 = fmaf(t.y, t.y, s2); s2 = fmaf(t.z, t.z, s2); s2 = fmaf(t.w, t.w, s2);
        float a[PP];
#pragma unroll
        for (int p = 0; p < PP; ++p) {
            float v = t.x * gf[p].x;
            v = fmaf(t.y, gf[p].y, v);
            v = fmaf(t.z, gf[p].z, v);
            v = fmaf(t.w, gf[p].w, v);
            a[p] = v;
        }
        // 64-lane butterfly reduce of 12 values
#pragma unroll
        for (int off = 32; off > 0; off >>= 1) {
            s1 += __shfl_xor(s1, off);
            s2 += __shfl_xor(s2, off);
#pragma unroll
            for (int p = 0; p < PP; ++p) a[p] += __shfl_xor(a[p], off);
        }
        if ((tid & 63) == 0) {
            const int wv = tid >> 6;
            red[wv][0] = s1; red[wv][1] = s2;
#pragma unroll
            for (int p = 0; p < PP; ++p) red[wv][2 + p] = a[p];
        }
        __syncthreads();
        if (tid < 12) {
            float f = 0.f;
#pragma unroll
            for (int q = 0; q < 7; ++q) f += red[q][tid];
            const float mu = __shfl(f, 0) * (1.0f / (float)DD);
            const float ms = __shfl(f, 1) * (1.0f / (float)DD);
            const float istd = rsqrtf(ms - mu * mu + 1e-5f);
            if (tid >= 2) {
                const int p = tid - 2;
                const float z = istd * (f - mu * SG[p]) + ZC[p];
                wlds[r][p] = 1.0f / (1.0f + __expf(-z));
            }
        }
        __syncthreads();
    }

    // ---- phase 2: out = X + w @ bank ----
    float4 bk[PP];
#pragma unroll
    for (int p = 0; p < PP; ++p) bk[p] = B4[(b * PP + p) * DQ + tid];

#pragma unroll 4
    for (int r = MROWS - 1; r >= 0; --r) {
        const int idx = ((n0 + r) * BB + b) * DQ + tid;
        float4 acc = X4[idx];
#pragma unroll
        for (int p = 0; p < PP; ++p) {
            const float wv = wlds[r][p];
            acc.x = fmaf(wv, bk[p].x, acc.x);
            acc.y = fmaf(wv, bk[p].y, acc.y);
            acc.z = fmaf(wv, bk[p].z, acc.z);
            acc.w = fmaf(wv, bk[p].w, acc.w);
        }
        O4[idx] = acc;
    }
}

// ---------------------------------------------------------------------------
extern "C" void kernel_launch(void* const* d_in, const int* in_sizes, int n_in,
                              void* d_out, int out_size, void* d_ws, size_t ws_size,
                              hipStream_t stream) {
    const float* X     = (const float*)d_in[0];
    const float* task  = (const float*)d_in[1];
    const float* Wtok  = (const float*)d_in[2];
    const float* btok  = (const float*)d_in[3];
    const float* Wptok = (const float*)d_in[4];
    const float* bptok = (const float*)d_in[5];
    const float* gamma = (const float*)d_in[6];
    const float* beta  = (const float*)d_in[7];
    const float* Wnet  = (const float*)d_in[8];
    const float* bnet  = (const float*)d_in[9];
    float* out = (float*)d_out;

    float* ws = (float*)d_ws;
    float* bank = ws;                                  // B*P*D = 4,587,520
    float* ptok = ws + (size_t)BB * PP * DD;           // B*D   =   458,752
    float* GF   = ptok + (size_t)BB * DD;              // P*D   =    17,920
    float* SG   = GF + PP * DD;                        // P
    float* ZC   = SG + PP;                             // P

    prep_gf<<<PP, 256, 0, stream>>>(gamma, beta, Wnet, bnet, GF, SG, ZC);
    prep_bank<<<dim3(77, 8), 256, 0, stream>>>(task, Wtok, btok, Wptok, bptok, bank, ptok);
    main_kernel<<<dim3(NCHUNK, BB), 448, 0, stream>>>(X, bank, ptok, GF, SG, ZC, out);
}

// Round 2
// 103.828 us; speedup vs baseline: 1.4791x; 1.4791x over previous
//
#include <hip/hip_runtime.h>
#include <hip/hip_bf16.h>

// Problem constants
#define NN 64
#define BB 256
#define DD 1792
#define KK 35
#define PP 10
#define DQ 448          // D / 4 (float4s per row)
#define MROWS 16        // n-rows per main block
#define NCHUNK 4        // N / MROWS

// DPP-based wave64 reduction step: x += dpp(x). All on the VALU pipe.
#define DPP_ADD(x, ctrl, rmask)                                                      \
    x += __int_as_float(__builtin_amdgcn_update_dpp(0, __float_as_int(x),            \
                                                    (ctrl), (rmask), 0xf, false))

// Full wave64 sum -> result valid in lane 63.
__device__ __forceinline__ float wave_sum_dpp(float x) {
    DPP_ADD(x, 0x111, 0xf);   // row_shr:1
    DPP_ADD(x, 0x112, 0xf);   // row_shr:2
    DPP_ADD(x, 0x114, 0xf);   // row_shr:4
    DPP_ADD(x, 0x118, 0xf);   // row_shr:8  -> lane15/31/47/63 hold row sums
    DPP_ADD(x, 0x142, 0xa);   // row_bcast:15 into rows 1,3
    DPP_ADD(x, 0x143, 0xc);   // row_bcast:31 into rows 2,3 -> lane 63 total
    return x;
}

// ---------------------------------------------------------------------------
// K1: Gf = gamma * W_net (P x D), sG[p] = sum(Gf[p]), zc[p] = dot(beta,Wnet[p]) + b_net[p]
// ---------------------------------------------------------------------------
__global__ void prep_gf(const float* __restrict__ gamma, const float* __restrict__ beta,
                        const float* __restrict__ Wnet, const float* __restrict__ bnet,
                        float* __restrict__ GF, float* __restrict__ SG, float* __restrict__ ZC) {
    const int p = blockIdx.x;
    const int tid = threadIdx.x;
    float sg = 0.f, sb = 0.f;
#pragma unroll
    for (int j = 0; j < 7; ++j) {
        int d = j * 256 + tid;
        float wv = Wnet[p * DD + d];
        float g = gamma[d] * wv;
        GF[p * DD + d] = g;
        sg += g;
        sb += beta[d] * wv;
    }
#pragma unroll
    for (int off = 32; off > 0; off >>= 1) {
        sg += __shfl_xor(sg, off);
        sb += __shfl_xor(sb, off);
    }
    __shared__ float rs[4][2];
    if ((tid & 63) == 0) { rs[tid >> 6][0] = sg; rs[tid >> 6][1] = sb; }
    __syncthreads();
    if (tid == 0) {
        float a = 0.f, c = 0.f;
#pragma unroll
        for (int w = 0; w < 4; ++w) { a += rs[w][0]; c += rs[w][1]; }
        SG[p] = a;
        ZC[p] = c + bnet[p];
    }
}

// ---------------------------------------------------------------------------
// K2: bank[b][r] = dot(task[b], Wtok[r]) + btok[r]; ptok[b][d] likewise.
// ---------------------------------------------------------------------------
__global__ void prep_bank(const float* __restrict__ task,
                          const float* __restrict__ Wtok, const float* __restrict__ btok,
                          const float* __restrict__ Wptok, const float* __restrict__ bptok,
                          float* __restrict__ bank, float* __restrict__ ptok) {
    __shared__ float ti[32 * KK];
    const int tid = threadIdx.x;
    const int b0 = blockIdx.y * 32;
    for (int i = tid; i < 32 * KK; i += 256) ti[i] = task[b0 * KK + i];

    const int r = blockIdx.x * 256 + tid;
    const bool isbank = (r < PP * DD);
    const int rr = isbank ? r : (r - PP * DD);
    const float* __restrict__ W = isbank ? Wtok : Wptok;
    const float bias = isbank ? btok[r] : bptok[rr];

    float w[KK];
#pragma unroll
    for (int k = 0; k < KK; ++k) w[k] = W[rr * KK + k];

    __syncthreads();
#pragma unroll 1
    for (int bb = 0; bb < 32; ++bb) {
        float acc = bias;
#pragma unroll
        for (int k = 0; k < KK; ++k) acc = fmaf(ti[bb * KK + k], w[k], acc);
        const int b = b0 + bb;
        if (isbank) bank[b * (PP * DD) + r] = acc;
        else        ptok[b * DD + rr]       = acc;
    }
}

// ---------------------------------------------------------------------------
// K3 (main): per block: b fixed, 16 n-rows, 448 threads, 1 float4/thread/row.
// Phase 1 (sync-free): per row, per-thread partials {s1,s2,10 dots} -> DPP
// wave reduce -> lane 63 writes 3 float4 partials to red[r][wave].
// Then ONE barrier; 256-thread stage finalizes all 16 rows' sigmoid weights.
// Phase 2: out = X + w @ bank, bank cached in 10 float4 regs.
// ---------------------------------------------------------------------------
__global__ __launch_bounds__(448) void main_kernel(
    const float* __restrict__ X, const float* __restrict__ BANK,
    const float* __restrict__ PTOK, const float* __restrict__ GF,
    const float* __restrict__ SG, const float* __restrict__ ZC,
    float* __restrict__ OUT) {
    const int tid = threadIdx.x;
    const int b = blockIdx.y;
    const int n0 = blockIdx.x * MROWS;
    const int wv = tid >> 6;

    const float4* __restrict__ X4 = (const float4*)X;
    const float4* __restrict__ B4 = (const float4*)BANK;
    const float4* __restrict__ G4 = (const float4*)GF;
    const float4* __restrict__ P4 = (const float4*)PTOK;
    float4* __restrict__ O4 = (float4*)OUT;

    __shared__ float red[MROWS][7][12];   // per-row, per-wave partials
    __shared__ float wlds[MROWS][PP];

    float4 gf[PP];
#pragma unroll
    for (int p = 0; p < PP; ++p) gf[p] = G4[p * DQ + tid];
    const float4 ptk = P4[b * DQ + tid];

    // ---- phase 1: sync-free partial accumulation ----
    float4 xn = X4[((n0 + 0) * BB + b) * DQ + tid];
#pragma unroll 1
    for (int r = 0; r < MROWS; ++r) {
        float4 x = xn;
        if (r < MROWS - 1) xn = X4[((n0 + r + 1) * BB + b) * DQ + tid];

        float4 t;
        t.x = x.x + ptk.x; t.y = x.y + ptk.y; t.z = x.z + ptk.z; t.w = x.w + ptk.w;

        float s1 = t.x + t.y + t.z + t.w;
        float s2 = t.x * t.x;
        s2 = fmaf(t.y, t.y, s2); s2 = fmaf(t.z, t.z, s2); s2 = fmaf(t.w, t.w, s2);
        float a[PP];
#pragma unroll
        for (int p = 0; p < PP; ++p) {
            float v = t.x * gf[p].x;
            v = fmaf(t.y, gf[p].y, v);
            v = fmaf(t.z, gf[p].z, v);
            v = fmaf(t.w, gf[p].w, v);
            a[p] = v;
        }
        // DPP reductions (VALU pipe only); totals land in lane 63
        s1 = wave_sum_dpp(s1);
        s2 = wave_sum_dpp(s2);
#pragma unroll
        for (int p = 0; p < PP; ++p) a[p] = wave_sum_dpp(a[p]);

        if ((tid & 63) == 63) {
            float4* dst = (float4*)&red[r][wv][0];
            dst[0] = make_float4(s1, s2, a[0], a[1]);
            dst[1] = make_float4(a[2], a[3], a[4], a[5]);
            dst[2] = make_float4(a[6], a[7], a[8], a[9]);
        }
    }
    __syncthreads();

    // ---- finalize all rows' weights in one stage ----
    if (tid < 256) {
        const int row = tid >> 4;
        const int v = tid & 15;
        float f = 0.f;
        if (v < 12) {
#pragma unroll
            for (int w = 0; w < 7; ++w) f += red[row][w][v];
        }
        const int base = (tid & 63) & ~15;          // lane holding v=0 in this wave
        const float mu = __shfl(f, base)     * (1.0f / (float)DD);
        const float ms = __shfl(f, base + 1) * (1.0f / (float)DD);
        const float istd = rsqrtf(ms - mu * mu + 1e-5f);
        if (v >= 2 && v < 12) {
            const int p = v - 2;
            const float z = istd * (f - mu * SG[p]) + ZC[p];
            wlds[row][p] = 1.0f / (1.0f + __expf(-z));
        }
    }
    __syncthreads();

    // ---- phase 2: out = X + w @ bank ----
    float4 bk[PP];
#pragma unroll
    for (int p = 0; p < PP; ++p) bk[p] = B4[(b * PP + p) * DQ + tid];

#pragma unroll 4
    for (int r = MROWS - 1; r >= 0; --r) {
        const int idx = ((n0 + r) * BB + b) * DQ + tid;
        float4 acc = X4[idx];
#pragma unroll
        for (int p = 0; p < PP; ++p) {
            const float wv2 = wlds[r][p];
            acc.x = fmaf(wv2, bk[p].x, acc.x);
            acc.y = fmaf(wv2, bk[p].y, acc.y);
            acc.z = fmaf(wv2, bk[p].z, acc.z);
            acc.w = fmaf(wv2, bk[p].w, acc.w);
        }
        O4[idx] = acc;
    }
}

// ---------------------------------------------------------------------------
extern "C" void kernel_launch(void* const* d_in, const int* in_sizes, int n_in,
                              void* d_out, int out_size, void* d_ws, size_t ws_size,
                              hipStream_t stream) {
    const float* X     = (const float*)d_in[0];
    const float* task  = (const float*)d_in[1];
    const float* Wtok  = (const float*)d_in[2];
    const float* btok  = (const float*)d_in[3];
    const float* Wptok = (const float*)d_in[4];
    const float* bptok = (const float*)d_in[5];
    const float* gamma = (const float*)d_in[6];
    const float* beta  = (const float*)d_in[7];
    const float* Wnet  = (const float*)d_in[8];
    const float* bnet  = (const float*)d_in[9];
    float* out = (float*)d_out;

    float* ws = (float*)d_ws;
    float* bank = ws;                                  // B*P*D = 4,587,520
    float* ptok = ws + (size_t)BB * PP * DD;           // B*D   =   458,752
    float* GF   = ptok + (size_t)BB * DD;              // P*D   =    17,920
    float* SG   = GF + PP * DD;                        // P
    float* ZC   = SG + PP;                             // P

    prep_gf<<<PP, 256, 0, stream>>>(gamma, beta, Wnet, bnet, GF, SG, ZC);
    prep_bank<<<dim3(77, 8), 256, 0, stream>>>(task, Wtok, btok, Wptok, bptok, bank, ptok);
    main_kernel<<<dim3(NCHUNK, BB), 448, 0, stream>>>(X, bank, ptok, GF, SG, ZC, out);
}

// Round 3
// 91.927 us; speedup vs baseline: 1.6706x; 1.1295x over previous
//
#include <hip/hip_runtime.h>
#include <hip/hip_bf16.h>

// Problem constants
#define NN 64
#define BB 256
#define DD 1792
#define KK 35
#define PP 10
#define DQ 448          // D / 4 (float4s per row)
#define MROWS 16        // n-rows per main block
#define NCHUNK 4        // N / MROWS
#define NGRP 28         // 16-lane groups per block (448/16)

// Single-instruction DPP add: x = dpp_shifted(x) + x.
// 4-step sequence leaves the 16-lane-group sum in lane 15 of each group.
// (Invalid-source lanes are identical under either bound_ctrl semantics here.)
__device__ __forceinline__ float group16_sum_dpp(float x) {
    asm("v_add_f32_dpp %0, %0, %0 row_shr:1 row_mask:0xf bank_mask:0xf bound_ctrl:0" : "+v"(x));
    asm("v_add_f32_dpp %0, %0, %0 row_shr:2 row_mask:0xf bank_mask:0xf bound_ctrl:0" : "+v"(x));
    asm("v_add_f32_dpp %0, %0, %0 row_shr:4 row_mask:0xf bank_mask:0xf bound_ctrl:0" : "+v"(x));
    asm("v_add_f32_dpp %0, %0, %0 row_shr:8 row_mask:0xf bank_mask:0xf bound_ctrl:0" : "+v"(x));
    return x;
}

// ---------------------------------------------------------------------------
// K1: Gf = gamma * W_net (P x D), sG[p] = sum(Gf[p]), zc[p] = dot(beta,Wnet[p]) + b_net[p]
// ---------------------------------------------------------------------------
__global__ void prep_gf(const float* __restrict__ gamma, const float* __restrict__ beta,
                        const float* __restrict__ Wnet, const float* __restrict__ bnet,
                        float* __restrict__ GF, float* __restrict__ SG, float* __restrict__ ZC) {
    const int p = blockIdx.x;
    const int tid = threadIdx.x;
    float sg = 0.f, sb = 0.f;
#pragma unroll
    for (int j = 0; j < 7; ++j) {
        int d = j * 256 + tid;
        float wv = Wnet[p * DD + d];
        float g = gamma[d] * wv;
        GF[p * DD + d] = g;
        sg += g;
        sb += beta[d] * wv;
    }
#pragma unroll
    for (int off = 32; off > 0; off >>= 1) {
        sg += __shfl_xor(sg, off);
        sb += __shfl_xor(sb, off);
    }
    __shared__ float rs[4][2];
    if ((tid & 63) == 0) { rs[tid >> 6][0] = sg; rs[tid >> 6][1] = sb; }
    __syncthreads();
    if (tid == 0) {
        float a = 0.f, c = 0.f;
#pragma unroll
        for (int w = 0; w < 4; ++w) { a += rs[w][0]; c += rs[w][1]; }
        SG[p] = a;
        ZC[p] = c + bnet[p];
    }
}

// ---------------------------------------------------------------------------
// K2: bank[b][r] = dot(task[b], Wtok[r]) + btok[r]; ptok[b][d] likewise.
// ---------------------------------------------------------------------------
__global__ void prep_bank(const float* __restrict__ task,
                          const float* __restrict__ Wtok, const float* __restrict__ btok,
                          const float* __restrict__ Wptok, const float* __restrict__ bptok,
                          float* __restrict__ bank, float* __restrict__ ptok) {
    __shared__ float ti[32 * KK];
    const int tid = threadIdx.x;
    const int b0 = blockIdx.y * 32;
    for (int i = tid; i < 32 * KK; i += 256) ti[i] = task[b0 * KK + i];

    const int r = blockIdx.x * 256 + tid;
    const bool isbank = (r < PP * DD);
    const int rr = isbank ? r : (r - PP * DD);
    const float* __restrict__ W = isbank ? Wtok : Wptok;
    const float bias = isbank ? btok[r] : bptok[rr];

    float w[KK];
#pragma unroll
    for (int k = 0; k < KK; ++k) w[k] = W[rr * KK + k];

    __syncthreads();
#pragma unroll 1
    for (int bb = 0; bb < 32; ++bb) {
        float acc = bias;
#pragma unroll
        for (int k = 0; k < KK; ++k) acc = fmaf(ti[bb * KK + k], w[k], acc);
        const int b = b0 + bb;
        if (isbank) bank[b * (PP * DD) + r] = acc;
        else        ptok[b * DD + rr]       = acc;
    }
}

// ---------------------------------------------------------------------------
// K3 (main): per block: b fixed, 16 n-rows, 448 threads, 1 float4/thread/row.
// Phase 1 (sync-free): per row, per-thread partials {s1,s2,10 dots} -> 4-step
// DPP reduce to 16-lane-group sums -> lane 15 of each group writes 3 float4
// partials to red[r][g]. ONE barrier; final stage sums 28 groups per (row,v)
// and produces all 16 rows' sigmoid weights.
// Phase 2: out = X + w @ bank, bank cached in 10 float4 regs.
// ---------------------------------------------------------------------------
__global__ __launch_bounds__(448) void main_kernel(
    const float* __restrict__ X, const float* __restrict__ BANK,
    const float* __restrict__ PTOK, const float* __restrict__ GF,
    const float* __restrict__ SG, const float* __restrict__ ZC,
    float* __restrict__ OUT) {
    const int tid = threadIdx.x;
    const int b = blockIdx.y;
    const int n0 = blockIdx.x * MROWS;

    const float4* __restrict__ X4 = (const float4*)X;
    const float4* __restrict__ B4 = (const float4*)BANK;
    const float4* __restrict__ G4 = (const float4*)GF;
    const float4* __restrict__ P4 = (const float4*)PTOK;
    float4* __restrict__ O4 = (float4*)OUT;

    __shared__ float red[MROWS][NGRP][12];   // per-row, per-16-lane-group partials
    __shared__ float wlds[MROWS][PP];

    float4 gf[PP];
#pragma unroll
    for (int p = 0; p < PP; ++p) gf[p] = G4[p * DQ + tid];
    const float4 ptk = P4[b * DQ + tid];

    const bool writer = ((tid & 15) == 15);
    const int g = tid >> 4;                  // group id 0..27

    // ---- phase 1: sync-free partial accumulation ----
    float4 xn = X4[((n0 + 0) * BB + b) * DQ + tid];
#pragma unroll 1
    for (int r = 0; r < MROWS; ++r) {
        float4 x = xn;
        if (r < MROWS - 1) xn = X4[((n0 + r + 1) * BB + b) * DQ + tid];

        float4 t;
        t.x = x.x + ptk.x; t.y = x.y + ptk.y; t.z = x.z + ptk.z; t.w = x.w + ptk.w;

        float s1 = t.x + t.y + t.z + t.w;
        float s2 = t.x * t.x;
        s2 = fmaf(t.y, t.y, s2); s2 = fmaf(t.z, t.z, s2); s2 = fmaf(t.w, t.w, s2);
        float a[PP];
#pragma unroll
        for (int p = 0; p < PP; ++p) {
            float v = t.x * gf[p].x;
            v = fmaf(t.y, gf[p].y, v);
            v = fmaf(t.z, gf[p].z, v);
            v = fmaf(t.w, gf[p].w, v);
            a[p] = v;
        }
        // 4-step DPP group reduction (1 VALU instr per step per value)
        s1 = group16_sum_dpp(s1);
        s2 = group16_sum_dpp(s2);
#pragma unroll
        for (int p = 0; p < PP; ++p) a[p] = group16_sum_dpp(a[p]);

        if (writer) {
            float4* dst = (float4*)&red[r][g][0];
            dst[0] = make_float4(s1, s2, a[0], a[1]);
            dst[1] = make_float4(a[2], a[3], a[4], a[5]);
            dst[2] = make_float4(a[6], a[7], a[8], a[9]);
        }
    }
    __syncthreads();

    // ---- finalize all rows' weights in one stage ----
    if (tid < 256) {
        const int row = tid >> 4;
        const int v = tid & 15;
        float f = 0.f;
        if (v < 12) {
#pragma unroll
            for (int q = 0; q < NGRP; ++q) f += red[row][q][v];
        }
        const int base = (tid & 63) & ~15;          // lane holding v=0 in this wave
        const float mu = __shfl(f, base)     * (1.0f / (float)DD);
        const float ms = __shfl(f, base + 1) * (1.0f / (float)DD);
        const float istd = rsqrtf(ms - mu * mu + 1e-5f);
        if (v >= 2 && v < 12) {
            const int p = v - 2;
            const float z = istd * (f - mu * SG[p]) + ZC[p];
            wlds[row][p] = 1.0f / (1.0f + __expf(-z));
        }
    }
    __syncthreads();

    // ---- phase 2: out = X + w @ bank ----
    float4 bk[PP];
#pragma unroll
    for (int p = 0; p < PP; ++p) bk[p] = B4[(b * PP + p) * DQ + tid];

#pragma unroll 4
    for (int r = MROWS - 1; r >= 0; --r) {
        const int idx = ((n0 + r) * BB + b) * DQ + tid;
        float4 acc = X4[idx];
#pragma unroll
        for (int p = 0; p < PP; ++p) {
            const float wv2 = wlds[r][p];
            acc.x = fmaf(wv2, bk[p].x, acc.x);
            acc.y = fmaf(wv2, bk[p].y, acc.y);
            acc.z = fmaf(wv2, bk[p].z, acc.z);
            acc.w = fmaf(wv2, bk[p].w, acc.w);
        }
        O4[idx] = acc;
    }
}

// ---------------------------------------------------------------------------
extern "C" void kernel_launch(void* const* d_in, const int* in_sizes, int n_in,
                              void* d_out, int out_size, void* d_ws, size_t ws_size,
                              hipStream_t stream) {
    const float* X     = (const float*)d_in[0];
    const float* task  = (const float*)d_in[1];
    const float* Wtok  = (const float*)d_in[2];
    const float* btok  = (const float*)d_in[3];
    const float* Wptok = (const float*)d_in[4];
    const float* bptok = (const float*)d_in[5];
    const float* gamma = (const float*)d_in[6];
    const float* beta  = (const float*)d_in[7];
    const float* Wnet  = (const float*)d_in[8];
    const float* bnet  = (const float*)d_in[9];
    float* out = (float*)d_out;

    float* ws = (float*)d_ws;
    float* bank = ws;                                  // B*P*D = 4,587,520
    float* ptok = ws + (size_t)BB * PP * DD;           // B*D   =   458,752
    float* GF   = ptok + (size_t)BB * DD;              // P*D   =    17,920
    float* SG   = GF + PP * DD;                        // P
    float* ZC   = SG + PP;                             // P

    prep_gf<<<PP, 256, 0, stream>>>(gamma, beta, Wnet, bnet, GF, SG, ZC);
    prep_bank<<<dim3(77, 8), 256, 0, stream>>>(task, Wtok, btok, Wptok, bptok, bank, ptok);
    main_kernel<<<dim3(NCHUNK, BB), 448, 0, stream>>>(X, bank, ptok, GF, SG, ZC, out);
}